// Round 15
// baseline (146.090 us; speedup 1.0000x reference)
//
#include <hip/hip_runtime.h>
#include <hip/hip_bf16.h>

#define B_ 2
#define T_ 2048
#define C_ 1024
#define H_ 16
#define D_ 64
#define M_ (B_*T_)          // 4096 rows
#define SCALE_ 0.125f       // 1/sqrt(64)
#define LOG2E_ 1.44269504f
#define NEG_ (-1e30f)
#define THR_ 8.0f           // defer-max threshold (log2 units)

typedef __bf16 bf16;
typedef __bf16 bf16x4 __attribute__((ext_vector_type(4)));
typedef __bf16 bf16x8 __attribute__((ext_vector_type(8)));
typedef float  f32x4  __attribute__((ext_vector_type(4)));

#define XB_ELEMS  ((size_t)M_*C_)        // 4,194,304
#define W_ELEMS   ((size_t)C_*C_)        // 1,048,576

__device__ __forceinline__ void glds16(const void* g, void* l) {
  __builtin_amdgcn_global_load_lds((const __attribute__((address_space(1))) void*)g,
                                   (__attribute__((address_space(3))) void*)l,
                                   16, 0, 0);
}

// ---------------------------------------------------------------------------
// f32 -> bf16 conversion pass (unchanged).
// ---------------------------------------------------------------------------
__global__ __launch_bounds__(256)
void cvt5(const float* __restrict__ x,  const float* __restrict__ wq,
          const float* __restrict__ wk, const float* __restrict__ wv,
          const float* __restrict__ wo, bf16* __restrict__ out) {
  int bid = blockIdx.x;
  const float* src; bf16* dst; size_t off;
  if (bid < 2048)      { src = x;  dst = out;                         off = (size_t)bid*2048; }
  else if (bid < 2560) { src = wq; dst = out + XB_ELEMS;              off = (size_t)(bid-2048)*2048; }
  else if (bid < 3072) { src = wk; dst = out + XB_ELEMS +   W_ELEMS;  off = (size_t)(bid-2560)*2048; }
  else if (bid < 3584) { src = wv; dst = out + XB_ELEMS + 2*W_ELEMS;  off = (size_t)(bid-3072)*2048; }
  else                 { src = wo; dst = out + XB_ELEMS + 3*W_ELEMS;  off = (size_t)(bid-3584)*2048; }
  size_t i = off + (size_t)threadIdx.x * 8;
  f32x4 lo = *(const f32x4*)(src + i);
  f32x4 hi = *(const f32x4*)(src + i + 4);
  bf16x8 r;
  #pragma unroll
  for (int t = 0; t < 4; ++t) { r[t] = (bf16)lo[t]; r[t+4] = (bf16)hi[t]; }
  *(bf16x8*)(dst + i) = r;
}

// ---------------------------------------------------------------------------
// NT GEMM — EXACT round-11 structure (fastest measured: 48.7 us QKV).
// 128x128 tile, BK=32, 4 waves, glds16, linear LDS, 3D grid, no swizzle.
// OUTMODE 0: z=0 -> Q*(SCALE*log2e) [B,H,T,D]; z=1 -> K; z=2 -> V^T [B,H,D,T]
// OUTMODE 1: OUT = f32 [M,C]
// ---------------------------------------------------------------------------
template<int OUTMODE>
__global__ __launch_bounds__(256)
void gemm_nt(const bf16* __restrict__ Ab,
             const bf16* __restrict__ W0, const bf16* __restrict__ W1,
             const bf16* __restrict__ W2,
             void* __restrict__ O0v, void* __restrict__ O1v, void* __restrict__ O2v,
             int K) {
  __shared__ __align__(16) bf16 As[128*32];
  __shared__ __align__(16) bf16 Bs[128*32];

  const bf16* W = W0;
  void* Ov = O0v;
  bool vtrans = false;
  float oscale = 1.0f;
  if constexpr (OUTMODE == 0) {
    if (blockIdx.z == 0)      { oscale = SCALE_ * LOG2E_; }
    else if (blockIdx.z == 1) { W = W1; Ov = O1v; }
    else                      { W = W2; Ov = O2v; vtrans = true; }
  }

  const int m0 = blockIdx.y * 128, n0 = blockIdx.x * 128;
  const int tid = threadIdx.x, wid = tid >> 6, lane = tid & 63;
  const int wm = wid >> 1, wn = wid & 1;
  const int l15 = lane & 15, grp = lane >> 4;

  f32x4 acc[4][4] = {};

  const int lr = lane >> 2, lk = (lane & 3) * 8;
  const int c0 = wid, c1 = wid + 4;
  const bf16* Ag0 = Ab + (size_t)(m0 + c0*16 + lr) * K + lk;
  const bf16* Ag1 = Ab + (size_t)(m0 + c1*16 + lr) * K + lk;
  const bf16* Bg0 = W  + (size_t)(n0 + c0*16 + lr) * K + lk;
  const bf16* Bg1 = W  + (size_t)(n0 + c1*16 + lr) * K + lk;
  bf16* Al0 = As + c0*512; bf16* Al1 = As + c1*512;
  bf16* Bl0 = Bs + c0*512; bf16* Bl1 = Bs + c1*512;

  const int amRow = wm*64 + l15;
  const int bnRow = wn*64 + l15;
  const int kSlot = grp * 8;

  for (int k0 = 0; k0 < K; k0 += 32) {
    __syncthreads();
    glds16(Ag0 + k0, Al0);
    glds16(Ag1 + k0, Al1);
    glds16(Bg0 + k0, Bl0);
    glds16(Bg1 + k0, Bl1);
    __syncthreads();

    bf16x8 af[4], bfr[4];
    #pragma unroll
    for (int i = 0; i < 4; ++i) {
      af[i]  = *(const bf16x8*)(As + (amRow + i*16)*32 + kSlot);
      bfr[i] = *(const bf16x8*)(Bs + (bnRow + i*16)*32 + kSlot);
    }
    #pragma unroll
    for (int i = 0; i < 4; ++i)
      #pragma unroll
      for (int j = 0; j < 4; ++j)
        acc[i][j] = __builtin_amdgcn_mfma_f32_16x16x32_bf16(af[i], bfr[j], acc[i][j], 0, 0, 0);
  }

  const int rBase = m0 + wm*64 + grp * 4;
  const int cBase = n0 + wn*64 + l15;
  #pragma unroll
  for (int fm = 0; fm < 4; ++fm) {
    #pragma unroll
    for (int fn = 0; fn < 4; ++fn) {
      #pragma unroll
      for (int j = 0; j < 4; ++j) {
        int m = rBase + fm*16 + j;
        int n = cBase + fn*16;
        if constexpr (OUTMODE == 0) {
          int b = m >> 11, t = m & 2047, h = n >> 6, d = n & 63;
          size_t idx = vtrans ? (((size_t)(b*H_ + h) * D_ + d) * T_ + t)
                              : (((size_t)(b*H_ + h) * T_ + t) * D_ + d);
          ((bf16*)Ov)[idx] = (bf16)(acc[fm][fn][j] * oscale);
        } else {
          ((float*)Ov)[(size_t)m * C_ + n] = acc[fm][fn][j];
        }
      }
    }
  }
}

// ---------------------------------------------------------------------------
// Flash attention, causal. QBLK=128: 4 waves x 32 q-rows (2 rowsets of 16),
// KV tiles of 64 -> 32 MFMA per staged tile per wave. Grid 512, complement-
// paired LPT: qt = id<256 ? 15-(id>>5) : (id-256)>>5  (CU pair sums to 34
// iters). bh = id&31 (XCD-coherent). Swapped-operand QK^T, defer-max, exp2.
// ---------------------------------------------------------------------------
#define LKV 72

__global__ __launch_bounds__(256)
void attn_fwd(const bf16* __restrict__ Q, const bf16* __restrict__ Km,
              const bf16* __restrict__ Vt, bf16* __restrict__ Oa) {
  __shared__ __align__(16) bf16 Ks [64*LKV];
  __shared__ __align__(16) bf16 Vts[64*LKV];
  __shared__ __align__(16) bf16 Ps [128*LKV];

  const int id = blockIdx.x;
  const int qt = (id < 256) ? (15 - (id >> 5)) : ((id - 256) >> 5);
  const int bh = id & 31;
  const int q0 = qt * 128;
  const int tid = threadIdx.x, wid = tid >> 6, lane = tid & 63;
  const int l15 = lane & 15;
  const int grp = lane >> 4;
  const int myrow4 = grp * 4;

  const bf16* Qb = Q  + (size_t)bh * T_ * D_;
  const bf16* Kb = Km + (size_t)bh * T_ * D_;
  const bf16* Vb = Vt + (size_t)bh * D_ * T_;

  const int ksr = tid >> 3, kskc = tid & 7;
  const int kSlot = grp * 8;
  const int b = bh >> 4, h = bh & 15;

  // Q fragments: 2 rowsets of 16 q-rows per wave
  const int r0 = q0 + wid*32 + l15;
  const int r1 = r0 + 16;
  bf16x8 aq00 = *(const bf16x8*)(Qb + (size_t)r0*64 +      grp*8);
  bf16x8 aq01 = *(const bf16x8*)(Qb + (size_t)r0*64 + 32 + grp*8);
  bf16x8 aq10 = *(const bf16x8*)(Qb + (size_t)r1*64 +      grp*8);
  bf16x8 aq11 = *(const bf16x8*)(Qb + (size_t)r1*64 + 32 + grp*8);

  f32x4 oacc[2][4] = {};
  float m_s[2] = {NEG_, NEG_}, l_s[2] = {0.f, 0.f};

  const int ktmax = 2*qt + 1;
  const int rowMax = q0 + wid*32 + 31;     // this wave's last q-row

  // prologue prefetch (tile 0)
  bf16x8 kv_a = *(const bf16x8*)(Kb + (size_t)(ksr)*64      + kskc*8);
  bf16x8 kv_b = *(const bf16x8*)(Kb + (size_t)(ksr + 32)*64 + kskc*8);
  bf16x8 vt_a = *(const bf16x8*)(Vb + (size_t)(ksr     )*T_ + kskc*8);
  bf16x8 vt_b = *(const bf16x8*)(Vb + (size_t)(ksr + 32)*T_ + kskc*8);

  for (int kt = 0; kt <= ktmax; ++kt) {
    const int kv0 = kt * 64;

    __syncthreads();
    *(bf16x8*)(Ks  + ksr*LKV      + kskc*8) = kv_a;
    *(bf16x8*)(Ks  + (ksr+32)*LKV + kskc*8) = kv_b;
    *(bf16x8*)(Vts + ksr*LKV      + kskc*8) = vt_a;
    *(bf16x8*)(Vts + (ksr+32)*LKV + kskc*8) = vt_b;
    __syncthreads();

    // prefetch next tile into regs (hides HBM/L2 latency under compute)
    {
      const int kn = (kt < ktmax) ? kv0 + 64 : kv0;
      kv_a = *(const bf16x8*)(Kb + (size_t)(kn + ksr)*64      + kskc*8);
      kv_b = *(const bf16x8*)(Kb + (size_t)(kn + ksr + 32)*64 + kskc*8);
      vt_a = *(const bf16x8*)(Vb + (size_t)(ksr     )*T_ + kn + kskc*8);
      vt_b = *(const bf16x8*)(Vb + (size_t)(ksr + 32)*T_ + kn + kskc*8);
    }

    if (kv0 <= rowMax) {                   // wave-uniform skip of dead tiles
      // S^T = K Q^T for both rowsets
      f32x4 s[2][4];
      __builtin_amdgcn_s_setprio(1);
      #pragma unroll
      for (int n = 0; n < 4; ++n) {
        int row = n*16 + l15;
        bf16x8 bk0 = *(const bf16x8*)(Ks + row*LKV      + kSlot);
        bf16x8 bk1 = *(const bf16x8*)(Ks + row*LKV + 32 + kSlot);
        f32x4 a0 = {}, a1 = {};
        a0 = __builtin_amdgcn_mfma_f32_16x16x32_bf16(bk0, aq00, a0, 0, 0, 0);
        a0 = __builtin_amdgcn_mfma_f32_16x16x32_bf16(bk1, aq01, a0, 0, 0, 0);
        a1 = __builtin_amdgcn_mfma_f32_16x16x32_bf16(bk0, aq10, a1, 0, 0, 0);
        a1 = __builtin_amdgcn_mfma_f32_16x16x32_bf16(bk1, aq11, a1, 0, 0, 0);
        s[0][n] = a0;
        s[1][n] = a1;
      }
      __builtin_amdgcn_s_setprio(0);

      // per-rowset: mask (only near diagonal), max, defer-max, p, P-write
      #pragma unroll
      for (int rs = 0; rs < 2; ++rs) {
        const int rbase = q0 + wid*32 + rs*16;     // wave-uniform
        const int qrow = rbase + l15;
        float pmax = NEG_;
        if (kv0 + 63 > rbase) {
          #pragma unroll
          for (int n = 0; n < 4; ++n)
            #pragma unroll
            for (int j = 0; j < 4; ++j) {
              int kvg = kv0 + n*16 + myrow4 + j;
              float sv = (kvg <= qrow) ? s[rs][n][j] : NEG_;
              s[rs][n][j] = sv;
              pmax = fmaxf(pmax, sv);
            }
        } else {
          #pragma unroll
          for (int n = 0; n < 4; ++n)
            #pragma unroll
            for (int j = 0; j < 4; ++j) pmax = fmaxf(pmax, s[rs][n][j]);
        }
        pmax = fmaxf(pmax, __shfl_xor(pmax, 16));
        pmax = fmaxf(pmax, __shfl_xor(pmax, 32));

        if (__any(pmax > m_s[rs] + THR_)) {
          float mnew = fmaxf(m_s[rs], pmax);
          float scold = __builtin_amdgcn_exp2f(m_s[rs] - mnew);
          m_s[rs] = mnew;
          l_s[rs] *= scold;
          #pragma unroll
          for (int j = 0; j < 4; ++j) {
            float scj = __shfl(scold, myrow4 + j);
            #pragma unroll
            for (int n = 0; n < 4; ++n) oacc[rs][n][j] *= scj;
          }
        }

        float ps = 0.f;
        #pragma unroll
        for (int n = 0; n < 4; ++n) {
          bf16x4 pw;
          #pragma unroll
          for (int j = 0; j < 4; ++j) {
            float p = __builtin_amdgcn_exp2f(s[rs][n][j] - m_s[rs]);
            ps += p;
            pw[j] = (bf16)p;
          }
          *(bf16x4*)(Ps + (size_t)(wid*32 + rs*16 + l15)*LKV + n*16 + myrow4) = pw;
        }
        ps += __shfl_xor(ps, 16);
        ps += __shfl_xor(ps, 32);
        l_s[rs] += ps;
      }

      asm volatile("s_waitcnt lgkmcnt(0)" ::: "memory");
      __builtin_amdgcn_sched_barrier(0);

      // O += P V for both rowsets (V fragments reused 2x)
      bf16x8 pa00 = *(const bf16x8*)(Ps + (size_t)(wid*32      + l15)*LKV      + kSlot);
      bf16x8 pa01 = *(const bf16x8*)(Ps + (size_t)(wid*32      + l15)*LKV + 32 + kSlot);
      bf16x8 pa10 = *(const bf16x8*)(Ps + (size_t)(wid*32 + 16 + l15)*LKV      + kSlot);
      bf16x8 pa11 = *(const bf16x8*)(Ps + (size_t)(wid*32 + 16 + l15)*LKV + 32 + kSlot);
      __builtin_amdgcn_s_setprio(1);
      #pragma unroll
      for (int n = 0; n < 4; ++n) {
        int vrow = n*16 + l15;
        bf16x8 bv0 = *(const bf16x8*)(Vts + vrow*LKV      + kSlot);
        bf16x8 bv1 = *(const bf16x8*)(Vts + vrow*LKV + 32 + kSlot);
        oacc[0][n] = __builtin_amdgcn_mfma_f32_16x16x32_bf16(pa00, bv0, oacc[0][n], 0, 0, 0);
        oacc[0][n] = __builtin_amdgcn_mfma_f32_16x16x32_bf16(pa01, bv1, oacc[0][n], 0, 0, 0);
        oacc[1][n] = __builtin_amdgcn_mfma_f32_16x16x32_bf16(pa10, bv0, oacc[1][n], 0, 0, 0);
        oacc[1][n] = __builtin_amdgcn_mfma_f32_16x16x32_bf16(pa11, bv1, oacc[1][n], 0, 0, 0);
      }
      __builtin_amdgcn_s_setprio(0);
    }
  }

  // epilogue: O /= l -> bf16 [B,T,C]
  #pragma unroll
  for (int rs = 0; rs < 2; ++rs) {
    const int tg = q0 + wid*32 + rs*16 + myrow4;
    #pragma unroll
    for (int j = 0; j < 4; ++j) {
      float lj = __shfl(l_s[rs], myrow4 + j);
      float inv = 1.f / lj;
      int trow = tg + j;
      #pragma unroll
      for (int n = 0; n < 4; ++n) {
        int ch = h*64 + n*16 + l15;
        Oa[((size_t)(b*T_ + trow)) * C_ + ch] = (bf16)(oacc[rs][n][j] * inv);
      }
    }
  }
}

// ---------------------------------------------------------------------------
extern "C" void kernel_launch(void* const* d_in, const int* in_sizes, int n_in,
                              void* d_out, int out_size, void* d_ws, size_t ws_size,
                              hipStream_t stream) {
  const float* x  = (const float*)d_in[0];
  const float* wq = (const float*)d_in[1];
  const float* wk = (const float*)d_in[2];
  const float* wv = (const float*)d_in[3];
  const float* wo = (const float*)d_in[4];

  bf16* q  = (bf16*)d_ws;                    // [B,H,T,D] bf16 (Q pre-scaled)
  bf16* k  = q  + XB_ELEMS;
  bf16* v  = k  + XB_ELEMS;                  // [B,H,D,T] bf16 (transposed)

  bf16* cvtbuf = (bf16*)d_out;               // bf16 staging inside d_out
  bf16* xb  = cvtbuf;                        // [M,K] bf16
  bf16* wqb = cvtbuf + XB_ELEMS;
  bf16* wkb = wqb + W_ELEMS;
  bf16* wvb = wkb + W_ELEMS;
  bf16* wob = wvb + W_ELEMS;                 // exactly fills d_out

  dim3 blk(256);
  // 0) convert all f32 inputs to bf16 (into d_out)
  cvt5<<<dim3(4096), blk, 0, stream>>>(x, wq, wk, wv, wo, cvtbuf);
  // 1) QKV projections (round-11 structure): xb @ W^T -> q,k,v
  gemm_nt<0><<<dim3(C_/128, M_/128, 3), blk, 0, stream>>>(xb, wqb, wkb, wvb,
                                                          q, k, v, C_);
  // 2) causal flash attention (QBLK=128, paired LPT) -> ao into xb slot
  attn_fwd<<<dim3(512), blk, 0, stream>>>(q, k, v, xb);
  // 3) relocate ao and wo_bf16 into ws (q,k slots dead after attention)
  hipMemcpyAsync(q, xb,  XB_ELEMS * sizeof(bf16), hipMemcpyDeviceToDevice, stream);
  hipMemcpyAsync(k, wob, W_ELEMS  * sizeof(bf16), hipMemcpyDeviceToDevice, stream);
  // 4) output projection: ao @ wo^T -> f32 d_out
  gemm_nt<1><<<dim3(C_/128, M_/128, 1), blk, 0, stream>>>(q, k, nullptr, nullptr,
                                                          d_out, nullptr, nullptr, C_);
}

// Round 16
// 126.797 us; speedup vs baseline: 1.1522x; 1.1522x over previous
//
#include <hip/hip_runtime.h>
#include <hip/hip_bf16.h>

#define B_ 2
#define T_ 2048
#define C_ 1024
#define H_ 16
#define D_ 64
#define M_ (B_*T_)          // 4096 rows
#define SCALE_ 0.125f       // 1/sqrt(64)
#define LOG2E_ 1.44269504f
#define NEG_ (-1e30f)
#define THR_ 8.0f           // defer-max threshold (log2 units)

typedef __bf16 bf16;
typedef __bf16 bf16x4 __attribute__((ext_vector_type(4)));
typedef __bf16 bf16x8 __attribute__((ext_vector_type(8)));
typedef float  f32x4  __attribute__((ext_vector_type(4)));

#define XB_ELEMS  ((size_t)M_*C_)        // 4,194,304
#define W_ELEMS   ((size_t)C_*C_)        // 1,048,576

__device__ __forceinline__ void glds16(const void* g, void* l) {
  __builtin_amdgcn_global_load_lds((const __attribute__((address_space(1))) void*)g,
                                   (__attribute__((address_space(3))) void*)l,
                                   16, 0, 0);
}

// ---------------------------------------------------------------------------
// f32 -> bf16 conversion pass. wo's destination is a separate pointer so the
// host can route it to ws (big-ws path) or d_out staging (fallback).
// ---------------------------------------------------------------------------
__global__ __launch_bounds__(256)
void cvt5(const float* __restrict__ x,  const float* __restrict__ wq,
          const float* __restrict__ wk, const float* __restrict__ wv,
          const float* __restrict__ wo, bf16* __restrict__ out,
          bf16* __restrict__ wodst) {
  int bid = blockIdx.x;
  const float* src; bf16* dst; size_t off;
  if (bid < 2048)      { src = x;  dst = out;                         off = (size_t)bid*2048; }
  else if (bid < 2560) { src = wq; dst = out + XB_ELEMS;              off = (size_t)(bid-2048)*2048; }
  else if (bid < 3072) { src = wk; dst = out + XB_ELEMS +   W_ELEMS;  off = (size_t)(bid-2560)*2048; }
  else if (bid < 3584) { src = wv; dst = out + XB_ELEMS + 2*W_ELEMS;  off = (size_t)(bid-3072)*2048; }
  else                 { src = wo; dst = wodst;                       off = (size_t)(bid-3584)*2048; }
  size_t i = off + (size_t)threadIdx.x * 8;
  f32x4 lo = *(const f32x4*)(src + i);
  f32x4 hi = *(const f32x4*)(src + i + 4);
  bf16x8 r;
  #pragma unroll
  for (int t = 0; t < 4; ++t) { r[t] = (bf16)lo[t]; r[t+4] = (bf16)hi[t]; }
  *(bf16x8*)(dst + i) = r;
}

// ---------------------------------------------------------------------------
// NT GEMM — round-11 structure (fastest measured: 48.7 us QKV).
// 128x128 tile, BK=32, 4 waves, glds16, linear LDS, 3D grid.
// OUTMODE 0: z=0 -> Q*(SCALE*log2e) [B,H,T,D]; z=1 -> K; z=2 -> V^T [B,H,D,T]
// OUTMODE 1: OUT = f32 [M,C]
// ---------------------------------------------------------------------------
template<int OUTMODE>
__global__ __launch_bounds__(256)
void gemm_nt(const bf16* __restrict__ Ab,
             const bf16* __restrict__ W0, const bf16* __restrict__ W1,
             const bf16* __restrict__ W2,
             void* __restrict__ O0v, void* __restrict__ O1v, void* __restrict__ O2v,
             int K) {
  __shared__ __align__(16) bf16 As[128*32];
  __shared__ __align__(16) bf16 Bs[128*32];

  const bf16* W = W0;
  void* Ov = O0v;
  bool vtrans = false;
  float oscale = 1.0f;
  if constexpr (OUTMODE == 0) {
    if (blockIdx.z == 0)      { oscale = SCALE_ * LOG2E_; }
    else if (blockIdx.z == 1) { W = W1; Ov = O1v; }
    else                      { W = W2; Ov = O2v; vtrans = true; }
  }

  const int m0 = blockIdx.y * 128, n0 = blockIdx.x * 128;
  const int tid = threadIdx.x, wid = tid >> 6, lane = tid & 63;
  const int wm = wid >> 1, wn = wid & 1;
  const int l15 = lane & 15, grp = lane >> 4;

  f32x4 acc[4][4] = {};

  const int lr = lane >> 2, lk = (lane & 3) * 8;
  const int c0 = wid, c1 = wid + 4;
  const bf16* Ag0 = Ab + (size_t)(m0 + c0*16 + lr) * K + lk;
  const bf16* Ag1 = Ab + (size_t)(m0 + c1*16 + lr) * K + lk;
  const bf16* Bg0 = W  + (size_t)(n0 + c0*16 + lr) * K + lk;
  const bf16* Bg1 = W  + (size_t)(n0 + c1*16 + lr) * K + lk;
  bf16* Al0 = As + c0*512; bf16* Al1 = As + c1*512;
  bf16* Bl0 = Bs + c0*512; bf16* Bl1 = Bs + c1*512;

  const int amRow = wm*64 + l15;
  const int bnRow = wn*64 + l15;
  const int kSlot = grp * 8;

  for (int k0 = 0; k0 < K; k0 += 32) {
    __syncthreads();
    glds16(Ag0 + k0, Al0);
    glds16(Ag1 + k0, Al1);
    glds16(Bg0 + k0, Bl0);
    glds16(Bg1 + k0, Bl1);
    __syncthreads();

    bf16x8 af[4], bfr[4];
    #pragma unroll
    for (int i = 0; i < 4; ++i) {
      af[i]  = *(const bf16x8*)(As + (amRow + i*16)*32 + kSlot);
      bfr[i] = *(const bf16x8*)(Bs + (bnRow + i*16)*32 + kSlot);
    }
    #pragma unroll
    for (int i = 0; i < 4; ++i)
      #pragma unroll
      for (int j = 0; j < 4; ++j)
        acc[i][j] = __builtin_amdgcn_mfma_f32_16x16x32_bf16(af[i], bfr[j], acc[i][j], 0, 0, 0);
  }

  const int rBase = m0 + wm*64 + grp * 4;
  const int cBase = n0 + wn*64 + l15;
  #pragma unroll
  for (int fm = 0; fm < 4; ++fm) {
    #pragma unroll
    for (int fn = 0; fn < 4; ++fn) {
      #pragma unroll
      for (int j = 0; j < 4; ++j) {
        int m = rBase + fm*16 + j;
        int n = cBase + fn*16;
        if constexpr (OUTMODE == 0) {
          int b = m >> 11, t = m & 2047, h = n >> 6, d = n & 63;
          size_t idx = vtrans ? (((size_t)(b*H_ + h) * D_ + d) * T_ + t)
                              : (((size_t)(b*H_ + h) * T_ + t) * D_ + d);
          ((bf16*)Ov)[idx] = (bf16)(acc[fm][fn][j] * oscale);
        } else {
          ((float*)Ov)[(size_t)m * C_ + n] = acc[fm][fn][j];
        }
      }
    }
  }
}

// ---------------------------------------------------------------------------
// Flash attention, causal — round-13 version (QBLK=64, grid 1024, LPT,
// XCD-coherent bh, swapped QK^T, defer-max, exp2, setprio).
// ---------------------------------------------------------------------------
#define LKV 72

__global__ __launch_bounds__(256)
void attn_fwd(const bf16* __restrict__ Q, const bf16* __restrict__ Km,
              const bf16* __restrict__ Vt, bf16* __restrict__ Oa) {
  __shared__ __align__(16) bf16 Ks [64*LKV];
  __shared__ __align__(16) bf16 Vts[64*LKV];
  __shared__ __align__(16) bf16 Ps [64*LKV];

  const int id = blockIdx.x;
  const int qt = 31 - (id >> 5);
  const int bh = id & 31;
  const int q0 = qt * 64;
  const int tid = threadIdx.x, wid = tid >> 6, lane = tid & 63;
  const int l15 = lane & 15;
  const int grp = lane >> 4;
  const int myrow4 = grp * 4;

  const bf16* Qb = Q  + (size_t)bh * T_ * D_;
  const bf16* Kb = Km + (size_t)bh * T_ * D_;
  const bf16* Vb = Vt + (size_t)bh * D_ * T_;

  const int ksr = tid >> 3, kskc = tid & 7;
  const int kSlot = grp * 8;
  const int b = bh >> 4, h = bh & 15;

  const int qrow = q0 + wid*16 + l15;
  bf16x8 aq0 = *(const bf16x8*)(Qb + (size_t)qrow*64 +      grp*8);
  bf16x8 aq1 = *(const bf16x8*)(Qb + (size_t)qrow*64 + 32 + grp*8);

  f32x4 oacc[4] = {};
  float m_s = NEG_, l_s = 0.f;

  bf16x8 kv_a = *(const bf16x8*)(Kb + (size_t)(ksr)*64      + kskc*8);
  bf16x8 kv_b = *(const bf16x8*)(Kb + (size_t)(ksr + 32)*64 + kskc*8);
  bf16x8 vt_a = *(const bf16x8*)(Vb + (size_t)(ksr     )*T_ + kskc*8);
  bf16x8 vt_b = *(const bf16x8*)(Vb + (size_t)(ksr + 32)*T_ + kskc*8);

  for (int kt = 0; kt <= qt; ++kt) {
    const int kv0 = kt * 64;

    __syncthreads();
    *(bf16x8*)(Ks  + ksr*LKV      + kskc*8) = kv_a;
    *(bf16x8*)(Ks  + (ksr+32)*LKV + kskc*8) = kv_b;
    *(bf16x8*)(Vts + ksr*LKV      + kskc*8) = vt_a;
    *(bf16x8*)(Vts + (ksr+32)*LKV + kskc*8) = vt_b;
    __syncthreads();

    {
      const int kn = (kt < qt) ? kv0 + 64 : kv0;
      kv_a = *(const bf16x8*)(Kb + (size_t)(kn + ksr)*64      + kskc*8);
      kv_b = *(const bf16x8*)(Kb + (size_t)(kn + ksr + 32)*64 + kskc*8);
      vt_a = *(const bf16x8*)(Vb + (size_t)(ksr     )*T_ + kn + kskc*8);
      vt_b = *(const bf16x8*)(Vb + (size_t)(ksr + 32)*T_ + kn + kskc*8);
    }

    f32x4 s[4];
    __builtin_amdgcn_s_setprio(1);
    #pragma unroll
    for (int n = 0; n < 4; ++n) {
      int row = n*16 + l15;
      bf16x8 bk0 = *(const bf16x8*)(Ks + row*LKV      + kSlot);
      bf16x8 bk1 = *(const bf16x8*)(Ks + row*LKV + 32 + kSlot);
      f32x4 a = {};
      a = __builtin_amdgcn_mfma_f32_16x16x32_bf16(bk0, aq0, a, 0, 0, 0);
      a = __builtin_amdgcn_mfma_f32_16x16x32_bf16(bk1, aq1, a, 0, 0, 0);
      s[n] = a;
    }
    __builtin_amdgcn_s_setprio(0);

    float pmax = NEG_;
    if (kt == qt) {
      #pragma unroll
      for (int n = 0; n < 4; ++n)
        #pragma unroll
        for (int j = 0; j < 4; ++j) {
          int kvg = kv0 + n*16 + myrow4 + j;
          float sv = (kvg <= qrow) ? s[n][j] : NEG_;
          s[n][j] = sv;
          pmax = fmaxf(pmax, sv);
        }
    } else {
      #pragma unroll
      for (int n = 0; n < 4; ++n)
        #pragma unroll
        for (int j = 0; j < 4; ++j) pmax = fmaxf(pmax, s[n][j]);
    }
    pmax = fmaxf(pmax, __shfl_xor(pmax, 16));
    pmax = fmaxf(pmax, __shfl_xor(pmax, 32));

    if (__any(pmax > m_s + THR_)) {
      float mnew = fmaxf(m_s, pmax);
      float scold = __builtin_amdgcn_exp2f(m_s - mnew);
      m_s = mnew;
      l_s *= scold;
      #pragma unroll
      for (int j = 0; j < 4; ++j) {
        float scj = __shfl(scold, myrow4 + j);
        #pragma unroll
        for (int n = 0; n < 4; ++n) oacc[n][j] *= scj;
      }
    }

    float ps = 0.f;
    #pragma unroll
    for (int n = 0; n < 4; ++n) {
      bf16x4 pw;
      #pragma unroll
      for (int j = 0; j < 4; ++j) {
        float p = __builtin_amdgcn_exp2f(s[n][j] - m_s);
        ps += p;
        pw[j] = (bf16)p;
      }
      *(bf16x4*)(Ps + (size_t)(wid*16 + l15)*LKV + n*16 + myrow4) = pw;
    }
    ps += __shfl_xor(ps, 16);
    ps += __shfl_xor(ps, 32);
    l_s += ps;

    asm volatile("s_waitcnt lgkmcnt(0)" ::: "memory");
    __builtin_amdgcn_sched_barrier(0);

    int parow = wid*16 + l15;
    bf16x8 pa0 = *(const bf16x8*)(Ps + parow*LKV      + kSlot);
    bf16x8 pa1 = *(const bf16x8*)(Ps + parow*LKV + 32 + kSlot);
    __builtin_amdgcn_s_setprio(1);
    #pragma unroll
    for (int n = 0; n < 4; ++n) {
      int vrow = n*16 + l15;
      bf16x8 bv0 = *(const bf16x8*)(Vts + vrow*LKV      + kSlot);
      bf16x8 bv1 = *(const bf16x8*)(Vts + vrow*LKV + 32 + kSlot);
      oacc[n] = __builtin_amdgcn_mfma_f32_16x16x32_bf16(pa0, bv0, oacc[n], 0, 0, 0);
      oacc[n] = __builtin_amdgcn_mfma_f32_16x16x32_bf16(pa1, bv1, oacc[n], 0, 0, 0);
    }
    __builtin_amdgcn_s_setprio(0);
  }

  const int tg = q0 + wid*16 + myrow4;
  #pragma unroll
  for (int j = 0; j < 4; ++j) {
    float lj = __shfl(l_s, myrow4 + j);
    float inv = 1.f / lj;
    int trow = tg + j;
    #pragma unroll
    for (int n = 0; n < 4; ++n) {
      int ch = h*64 + n*16 + l15;
      Oa[((size_t)(b*T_ + trow)) * C_ + ch] = (bf16)(oacc[n][j] * inv);
    }
  }
}

// ---------------------------------------------------------------------------
extern "C" void kernel_launch(void* const* d_in, const int* in_sizes, int n_in,
                              void* d_out, int out_size, void* d_ws, size_t ws_size,
                              hipStream_t stream) {
  const float* x  = (const float*)d_in[0];
  const float* wq = (const float*)d_in[1];
  const float* wk = (const float*)d_in[2];
  const float* wv = (const float*)d_in[3];
  const float* wo = (const float*)d_in[4];

  bf16* q  = (bf16*)d_ws;                    // [B,H,T,D] bf16 (Q pre-scaled)
  bf16* k  = q  + XB_ELEMS;
  bf16* v  = k  + XB_ELEMS;                  // [B,H,D,T] bf16 (transposed)

  bf16* cvtbuf = (bf16*)d_out;               // bf16 staging inside d_out
  bf16* xb  = cvtbuf;                        // [M,K] bf16
  bf16* wqb = cvtbuf + XB_ELEMS;
  bf16* wkb = wqb + W_ELEMS;
  bf16* wvb = wkb + W_ELEMS;
  bf16* wob_stage = wvb + W_ELEMS;           // fallback wo staging (in d_out)

  // Big-ws path: ao and wo-bf16 live in ws -> no relocation memcpys.
  const bool bigws = ws_size >= (4*XB_ELEMS + W_ELEMS) * sizeof(bf16);
  bf16* ao  = bigws ? (v + XB_ELEMS) : xb;           // attn output [B,T,C]
  bf16* wob = bigws ? (v + XB_ELEMS + XB_ELEMS) : wob_stage;

  dim3 blk(256);
  // 0) convert all f32 inputs to bf16
  cvt5<<<dim3(4096), blk, 0, stream>>>(x, wq, wk, wv, wo, cvtbuf, wob);
  // 1) QKV projections: xb @ W^T -> q,k,v
  gemm_nt<0><<<dim3(C_/128, M_/128, 3), blk, 0, stream>>>(xb, wqb, wkb, wvb,
                                                          q, k, v, C_);
  // 2) causal flash attention -> ao bf16 [B,T,C]
  attn_fwd<<<dim3(1024), blk, 0, stream>>>(q, k, v, ao);
  bf16* aoSrc = ao;
  if (!bigws) {
    // relocate ao and wo_bf16 into ws (q,k slots dead after attention)
    hipMemcpyAsync(q, xb,        XB_ELEMS * sizeof(bf16), hipMemcpyDeviceToDevice, stream);
    hipMemcpyAsync(k, wob_stage, W_ELEMS  * sizeof(bf16), hipMemcpyDeviceToDevice, stream);
    aoSrc = q; wob = k;
  }
  // 3) output projection: ao @ wo^T -> f32 d_out
  gemm_nt<1><<<dim3(C_/128, M_/128, 1), blk, 0, stream>>>(aoSrc, wob, nullptr, nullptr,
                                                          d_out, nullptr, nullptr, C_);
}

// Round 17
// 113.211 us; speedup vs baseline: 1.2904x; 1.1200x over previous
//
#include <hip/hip_runtime.h>
#include <hip/hip_bf16.h>

#define B_ 2
#define T_ 2048
#define C_ 1024
#define H_ 16
#define D_ 64
#define M_ (B_*T_)          // 4096 rows
#define SCALE_ 0.125f       // 1/sqrt(64)
#define LOG2E_ 1.44269504f
#define NEG_ (-1e30f)
#define THR_ 8.0f           // defer-max threshold (log2 units)

typedef __bf16 bf16;
typedef __bf16 bf16x4 __attribute__((ext_vector_type(4)));
typedef __bf16 bf16x8 __attribute__((ext_vector_type(8)));
typedef float  f32x4  __attribute__((ext_vector_type(4)));

#define XB_ELEMS  ((size_t)M_*C_)        // 4,194,304
#define W_ELEMS   ((size_t)C_*C_)        // 1,048,576

__device__ __forceinline__ void glds16(const void* g, void* l) {
  __builtin_amdgcn_global_load_lds((const __attribute__((address_space(1))) void*)g,
                                   (__attribute__((address_space(3))) void*)l,
                                   16, 0, 0);
}

// ---------------------------------------------------------------------------
// f32 -> bf16 conversion pass (r16 version).
// ---------------------------------------------------------------------------
__global__ __launch_bounds__(256)
void cvt5(const float* __restrict__ x,  const float* __restrict__ wq,
          const float* __restrict__ wk, const float* __restrict__ wv,
          const float* __restrict__ wo, bf16* __restrict__ out,
          bf16* __restrict__ wodst) {
  int bid = blockIdx.x;
  const float* src; bf16* dst; size_t off;
  if (bid < 2048)      { src = x;  dst = out;                         off = (size_t)bid*2048; }
  else if (bid < 2560) { src = wq; dst = out + XB_ELEMS;              off = (size_t)(bid-2048)*2048; }
  else if (bid < 3072) { src = wk; dst = out + XB_ELEMS +   W_ELEMS;  off = (size_t)(bid-2560)*2048; }
  else if (bid < 3584) { src = wv; dst = out + XB_ELEMS + 2*W_ELEMS;  off = (size_t)(bid-3072)*2048; }
  else                 { src = wo; dst = wodst;                       off = (size_t)(bid-3584)*2048; }
  size_t i = off + (size_t)threadIdx.x * 8;
  f32x4 lo = *(const f32x4*)(src + i);
  f32x4 hi = *(const f32x4*)(src + i + 4);
  bf16x8 r;
  #pragma unroll
  for (int t = 0; t < 4; ++t) { r[t] = (bf16)lo[t]; r[t+4] = (bf16)hi[t]; }
  *(bf16x8*)(dst + i) = r;
}

// ---------------------------------------------------------------------------
// NT GEMM: 128x128 tile, BK=64, 4 waves, single-buffered glds16 staging with
// pre-swizzled source + XOR-swizzled reads (both-sides, rule #21).
// 16 K-iterations (half the barrier/drain events of BK=32).
// OUTMODE 0: z=0 -> Q*(SCALE*log2e) [B,H,T,D]; z=1 -> K; z=2 -> V^T [B,H,D,T]
// OUTMODE 1: OUT = f32 [M,C]
// ---------------------------------------------------------------------------
template<int OUTMODE>
__global__ __launch_bounds__(256)
void gemm_nt(const bf16* __restrict__ Ab,
             const bf16* __restrict__ W0, const bf16* __restrict__ W1,
             const bf16* __restrict__ W2,
             void* __restrict__ O0v, void* __restrict__ O1v, void* __restrict__ O2v,
             int K) {
  __shared__ __align__(16) bf16 As[128*64];   // 16 KB, 128B rows
  __shared__ __align__(16) bf16 Bs[128*64];   // 16 KB

  const bf16* W = W0;
  void* Ov = O0v;
  bool vtrans = false;
  float oscale = 1.0f;
  if constexpr (OUTMODE == 0) {
    if (blockIdx.z == 0)      { oscale = SCALE_ * LOG2E_; }
    else if (blockIdx.z == 1) { W = W1; Ov = O1v; }
    else                      { W = W2; Ov = O2v; vtrans = true; }
  }

  const int m0 = blockIdx.y * 128, n0 = blockIdx.x * 128;
  const int tid = threadIdx.x, wid = tid >> 6, lane = tid & 63;
  const int wm = wid >> 1, wn = wid & 1;
  const int l15 = lane & 15, grp = lane >> 4;

  f32x4 acc[4][4] = {};

  // staging: 16 chunks/matrix (8 rows x 64k = 1KB); wave w -> chunks w+4c.
  // lane -> row_in_chunk = lane>>3, phys 16B-slot = lane&7.
  // Pre-swizzled source: logical slot = (lane&7) ^ (row&7), row&7 = lane>>3.
  const int lr8 = lane >> 3;
  const int lkswz = ((lane & 7) ^ lr8) * 8;           // global k-elem offset
  const bf16* Ag = Ab + (size_t)(m0 + wid*8 + lr8) * K + lkswz;
  const bf16* Bg = W  + (size_t)(n0 + wid*8 + lr8) * K + lkswz;

  const int amRow = wm*64 + l15;
  const int bnRow = wn*64 + l15;
  const int swz = l15 & 7;                            // row&7 for all reads

  for (int k0 = 0; k0 < K; k0 += 64) {
    __syncthreads();                    // prev iteration's LDS reads complete
    #pragma unroll
    for (int c = 0; c < 4; ++c) {
      glds16(Ag + (size_t)(c*32)*K + k0, As + (wid + c*4)*512);
      glds16(Bg + (size_t)(c*32)*K + k0, Bs + (wid + c*4)*512);
    }
    __syncthreads();                    // staged tile visible (vmcnt drained)

    #pragma unroll
    for (int ks = 0; ks < 2; ++ks) {
      const int aslot = ((ks*4 + grp) ^ swz) * 8;     // swizzled k-elem offset
      bf16x8 af[4], bfr[4];
      #pragma unroll
      for (int i = 0; i < 4; ++i) {
        af[i]  = *(const bf16x8*)(As + (amRow + i*16)*64 + aslot);
        bfr[i] = *(const bf16x8*)(Bs + (bnRow + i*16)*64 + aslot);
      }
      __builtin_amdgcn_s_setprio(1);
      #pragma unroll
      for (int i = 0; i < 4; ++i)
        #pragma unroll
        for (int j = 0; j < 4; ++j)
          acc[i][j] = __builtin_amdgcn_mfma_f32_16x16x32_bf16(af[i], bfr[j], acc[i][j], 0, 0, 0);
      __builtin_amdgcn_s_setprio(0);
    }
  }

  // epilogue: C/D layout col=lane&15, row=(lane>>4)*4+reg
  const int rBase = m0 + wm*64 + grp * 4;
  const int cBase = n0 + wn*64 + l15;
  #pragma unroll
  for (int fm = 0; fm < 4; ++fm) {
    #pragma unroll
    for (int fn = 0; fn < 4; ++fn) {
      #pragma unroll
      for (int j = 0; j < 4; ++j) {
        int m = rBase + fm*16 + j;
        int n = cBase + fn*16;
        if constexpr (OUTMODE == 0) {
          int b = m >> 11, t = m & 2047, h = n >> 6, d = n & 63;
          size_t idx = vtrans ? (((size_t)(b*H_ + h) * D_ + d) * T_ + t)
                              : (((size_t)(b*H_ + h) * T_ + t) * D_ + d);
          ((bf16*)Ov)[idx] = (bf16)(acc[fm][fn][j] * oscale);
        } else {
          ((float*)Ov)[(size_t)m * C_ + n] = acc[fm][fn][j];
        }
      }
    }
  }
}

// ---------------------------------------------------------------------------
// Flash attention, causal — round-13 version (unchanged from r16).
// ---------------------------------------------------------------------------
#define LKV 72

__global__ __launch_bounds__(256)
void attn_fwd(const bf16* __restrict__ Q, const bf16* __restrict__ Km,
              const bf16* __restrict__ Vt, bf16* __restrict__ Oa) {
  __shared__ __align__(16) bf16 Ks [64*LKV];
  __shared__ __align__(16) bf16 Vts[64*LKV];
  __shared__ __align__(16) bf16 Ps [64*LKV];

  const int id = blockIdx.x;
  const int qt = 31 - (id >> 5);
  const int bh = id & 31;
  const int q0 = qt * 64;
  const int tid = threadIdx.x, wid = tid >> 6, lane = tid & 63;
  const int l15 = lane & 15;
  const int grp = lane >> 4;
  const int myrow4 = grp * 4;

  const bf16* Qb = Q  + (size_t)bh * T_ * D_;
  const bf16* Kb = Km + (size_t)bh * T_ * D_;
  const bf16* Vb = Vt + (size_t)bh * D_ * T_;

  const int ksr = tid >> 3, kskc = tid & 7;
  const int kSlot = grp * 8;
  const int b = bh >> 4, h = bh & 15;

  const int qrow = q0 + wid*16 + l15;
  bf16x8 aq0 = *(const bf16x8*)(Qb + (size_t)qrow*64 +      grp*8);
  bf16x8 aq1 = *(const bf16x8*)(Qb + (size_t)qrow*64 + 32 + grp*8);

  f32x4 oacc[4] = {};
  float m_s = NEG_, l_s = 0.f;

  bf16x8 kv_a = *(const bf16x8*)(Kb + (size_t)(ksr)*64      + kskc*8);
  bf16x8 kv_b = *(const bf16x8*)(Kb + (size_t)(ksr + 32)*64 + kskc*8);
  bf16x8 vt_a = *(const bf16x8*)(Vb + (size_t)(ksr     )*T_ + kskc*8);
  bf16x8 vt_b = *(const bf16x8*)(Vb + (size_t)(ksr + 32)*T_ + kskc*8);

  for (int kt = 0; kt <= qt; ++kt) {
    const int kv0 = kt * 64;

    __syncthreads();
    *(bf16x8*)(Ks  + ksr*LKV      + kskc*8) = kv_a;
    *(bf16x8*)(Ks  + (ksr+32)*LKV + kskc*8) = kv_b;
    *(bf16x8*)(Vts + ksr*LKV      + kskc*8) = vt_a;
    *(bf16x8*)(Vts + (ksr+32)*LKV + kskc*8) = vt_b;
    __syncthreads();

    {
      const int kn = (kt < qt) ? kv0 + 64 : kv0;
      kv_a = *(const bf16x8*)(Kb + (size_t)(kn + ksr)*64      + kskc*8);
      kv_b = *(const bf16x8*)(Kb + (size_t)(kn + ksr + 32)*64 + kskc*8);
      vt_a = *(const bf16x8*)(Vb + (size_t)(ksr     )*T_ + kn + kskc*8);
      vt_b = *(const bf16x8*)(Vb + (size_t)(ksr + 32)*T_ + kn + kskc*8);
    }

    f32x4 s[4];
    __builtin_amdgcn_s_setprio(1);
    #pragma unroll
    for (int n = 0; n < 4; ++n) {
      int row = n*16 + l15;
      bf16x8 bk0 = *(const bf16x8*)(Ks + row*LKV      + kSlot);
      bf16x8 bk1 = *(const bf16x8*)(Ks + row*LKV + 32 + kSlot);
      f32x4 a = {};
      a = __builtin_amdgcn_mfma_f32_16x16x32_bf16(bk0, aq0, a, 0, 0, 0);
      a = __builtin_amdgcn_mfma_f32_16x16x32_bf16(bk1, aq1, a, 0, 0, 0);
      s[n] = a;
    }
    __builtin_amdgcn_s_setprio(0);

    float pmax = NEG_;
    if (kt == qt) {
      #pragma unroll
      for (int n = 0; n < 4; ++n)
        #pragma unroll
        for (int j = 0; j < 4; ++j) {
          int kvg = kv0 + n*16 + myrow4 + j;
          float sv = (kvg <= qrow) ? s[n][j] : NEG_;
          s[n][j] = sv;
          pmax = fmaxf(pmax, sv);
        }
    } else {
      #pragma unroll
      for (int n = 0; n < 4; ++n)
        #pragma unroll
        for (int j = 0; j < 4; ++j) pmax = fmaxf(pmax, s[n][j]);
    }
    pmax = fmaxf(pmax, __shfl_xor(pmax, 16));
    pmax = fmaxf(pmax, __shfl_xor(pmax, 32));

    if (__any(pmax > m_s + THR_)) {
      float mnew = fmaxf(m_s, pmax);
      float scold = __builtin_amdgcn_exp2f(m_s - mnew);
      m_s = mnew;
      l_s *= scold;
      #pragma unroll
      for (int j = 0; j < 4; ++j) {
        float scj = __shfl(scold, myrow4 + j);
        #pragma unroll
        for (int n = 0; n < 4; ++n) oacc[n][j] *= scj;
      }
    }

    float ps = 0.f;
    #pragma unroll
    for (int n = 0; n < 4; ++n) {
      bf16x4 pw;
      #pragma unroll
      for (int j = 0; j < 4; ++j) {
        float p = __builtin_amdgcn_exp2f(s[n][j] - m_s);
        ps += p;
        pw[j] = (bf16)p;
      }
      *(bf16x4*)(Ps + (size_t)(wid*16 + l15)*LKV + n*16 + myrow4) = pw;
    }
    ps += __shfl_xor(ps, 16);
    ps += __shfl_xor(ps, 32);
    l_s += ps;

    asm volatile("s_waitcnt lgkmcnt(0)" ::: "memory");
    __builtin_amdgcn_sched_barrier(0);

    int parow = wid*16 + l15;
    bf16x8 pa0 = *(const bf16x8*)(Ps + parow*LKV      + kSlot);
    bf16x8 pa1 = *(const bf16x8*)(Ps + parow*LKV + 32 + kSlot);
    __builtin_amdgcn_s_setprio(1);
    #pragma unroll
    for (int n = 0; n < 4; ++n) {
      int vrow = n*16 + l15;
      bf16x8 bv0 = *(const bf16x8*)(Vts + vrow*LKV      + kSlot);
      bf16x8 bv1 = *(const bf16x8*)(Vts + vrow*LKV + 32 + kSlot);
      oacc[n] = __builtin_amdgcn_mfma_f32_16x16x32_bf16(pa0, bv0, oacc[n], 0, 0, 0);
      oacc[n] = __builtin_amdgcn_mfma_f32_16x16x32_bf16(pa1, bv1, oacc[n], 0, 0, 0);
    }
    __builtin_amdgcn_s_setprio(0);
  }

  const int tg = q0 + wid*16 + myrow4;
  #pragma unroll
  for (int j = 0; j < 4; ++j) {
    float lj = __shfl(l_s, myrow4 + j);
    float inv = 1.f / lj;
    int trow = tg + j;
    #pragma unroll
    for (int n = 0; n < 4; ++n) {
      int ch = h*64 + n*16 + l15;
      Oa[((size_t)(b*T_ + trow)) * C_ + ch] = (bf16)(oacc[n][j] * inv);
    }
  }
}

// ---------------------------------------------------------------------------
extern "C" void kernel_launch(void* const* d_in, const int* in_sizes, int n_in,
                              void* d_out, int out_size, void* d_ws, size_t ws_size,
                              hipStream_t stream) {
  const float* x  = (const float*)d_in[0];
  const float* wq = (const float*)d_in[1];
  const float* wk = (const float*)d_in[2];
  const float* wv = (const float*)d_in[3];
  const float* wo = (const float*)d_in[4];

  bf16* q  = (bf16*)d_ws;                    // [B,H,T,D] bf16 (Q pre-scaled)
  bf16* k  = q  + XB_ELEMS;
  bf16* v  = k  + XB_ELEMS;                  // [B,H,D,T] bf16 (transposed)

  bf16* cvtbuf = (bf16*)d_out;               // bf16 staging inside d_out
  bf16* xb  = cvtbuf;                        // [M,K] bf16
  bf16* wqb = cvtbuf + XB_ELEMS;
  bf16* wkb = wqb + W_ELEMS;
  bf16* wvb = wkb + W_ELEMS;
  bf16* wob_stage = wvb + W_ELEMS;           // fallback wo staging (in d_out)

  // Big-ws path: ao and wo-bf16 live in ws -> no relocation memcpys.
  const bool bigws = ws_size >= (4*XB_ELEMS + W_ELEMS) * sizeof(bf16);
  bf16* ao  = bigws ? (v + XB_ELEMS) : xb;           // attn output [B,T,C]
  bf16* wob = bigws ? (v + XB_ELEMS + XB_ELEMS) : wob_stage;

  dim3 blk(256);
  // 0) convert all f32 inputs to bf16
  cvt5<<<dim3(4096), blk, 0, stream>>>(x, wq, wk, wv, wo, cvtbuf, wob);
  // 1) QKV projections (BK=64, swizzled): xb @ W^T -> q,k,v
  gemm_nt<0><<<dim3(C_/128, M_/128, 3), blk, 0, stream>>>(xb, wqb, wkb, wvb,
                                                          q, k, v, C_);
  // 2) causal flash attention -> ao bf16 [B,T,C]
  attn_fwd<<<dim3(1024), blk, 0, stream>>>(q, k, v, ao);
  bf16* aoSrc = ao;
  if (!bigws) {
    hipMemcpyAsync(q, xb,        XB_ELEMS * sizeof(bf16), hipMemcpyDeviceToDevice, stream);
    hipMemcpyAsync(k, wob_stage, W_ELEMS  * sizeof(bf16), hipMemcpyDeviceToDevice, stream);
    aoSrc = q; wob = k;
  }
  // 3) output projection: ao @ wo^T -> f32 d_out
  gemm_nt<1><<<dim3(C_/128, M_/128, 1), blk, 0, stream>>>(aoSrc, wob, nullptr, nullptr,
                                                          d_out, nullptr, nullptr, C_);
}